// Round 7
// baseline (135.768 us; speedup 1.0000x reference)
//
#include <hip/hip_runtime.h>
#include <math.h>

#define CT    320
#define NPTS  1024
#define DFEAT 256
#define DPOS  64
#define KSEL  32

// ============ Kernel C: per-point 1/max(||pos||,eps) -> rnjg (ws) ===========
// 64 blocks x 256 threads; block b: batch b>>2, j-segment (b&3)*256.
// Same fmaf chain order as before -> bitwise-identical rnj.
__global__ void gnn_rnj(const float* __restrict__ in, float* __restrict__ rnjg) {
  const int b     = blockIdx.x;
  const int batch = b >> 2;
  const int j     = ((b & 3) << 8) + threadIdx.x;
  const float* __restrict__ pbase = in + (size_t)batch * CT * NPTS + (size_t)DFEAT * NPTS;
  float s = 0.f;
#pragma unroll 8
  for (int d = 0; d < DPOS; ++d) {
    const float x = pbase[(size_t)d * NPTS + j];
    s = fmaf(x, x, s);
  }
  rnjg[batch * NPTS + j] = 1.0f / fmaxf(sqrtf(s), 1e-12f);
}

// ================= Kernel A: sim + exact top-32 + softmax -> pairs(ws) ======
// 2048 blocks x 256 threads; 8 rows/block; ~6 blocks/CU resident (TLP is the
// point: round-6 showed 54% stall at 32% occupancy). Wave owns 2 full rows
// (all 1024 j, 16 j/lane); top-32 exact per row from registers.
#define AROWS 8
__global__ __launch_bounds__(256, 6) void gnn_sim_topk(const float* __restrict__ in,
                                                       const float* __restrict__ rnjg,
                                                       float2* __restrict__ pairs) {
  __shared__ float pi[DPOS * 12];      // [d][i], 8 rows padded to 12
  __shared__ float rnjL[NPTS];
  __shared__ float cand[AROWS][68];    // 32 interleaved (v,j) pairs + pad

  const int p     = blockIdx.x;
  const int batch = ((p & 7) << 1) | ((p >> 3) & 1);   // same-batch -> same XCD
  const int chunk = p >> 4;            // 0..127
  const int i0    = chunk * AROWS;
  const int tid   = threadIdx.x;
  const int w     = tid >> 6;
  const int lane  = tid & 63;

  const float* __restrict__ pbase = in + (size_t)batch * CT * NPTS + (size_t)DFEAT * NPTS;

  // stage raw pos of the 8 rows: thread t -> (d = t>>3 (+32), i = t&7)
  {
    const int i = tid & 7;
    const int d0 = tid >> 3;           // 0..31
    pi[d0 * 12 + i]        = pbase[(size_t)d0 * NPTS + i0 + i];
    pi[(d0 + 32) * 12 + i] = pbase[(size_t)(d0 + 32) * NPTS + i0 + i];
  }
  // rnj table for this batch (4 KB)
  *(float4*)&rnjL[tid * 4] = *(const float4*)&rnjg[batch * NPTS + tid * 4];
  __syncthreads();

  // ---- sim: wave w owns rows {2w, 2w+1}; lane owns j = u*256 + lane*4 + t ----
  float acc[2][16];
#pragma unroll
  for (int r = 0; r < 2; ++r)
#pragma unroll
    for (int s = 0; s < 16; ++s) acc[r][s] = 0.f;

  const float* jp = pbase + lane * 4;
#pragma unroll 2
  for (int d = 0; d < DPOS; ++d) {
    const float2 pv2 = *(const float2*)&pi[d * 12 + w * 2];   // broadcast b64
    const float pr_[2] = {pv2.x, pv2.y};
    float4 jv[4];
#pragma unroll
    for (int u = 0; u < 4; ++u)
      jv[u] = *(const float4*)(jp + (size_t)d * NPTS + u * 256);
#pragma unroll
    for (int r = 0; r < 2; ++r) {
#pragma unroll
      for (int u = 0; u < 4; ++u) {
        acc[r][u*4+0] = fmaf(pr_[r], jv[u].x, acc[r][u*4+0]);
        acc[r][u*4+1] = fmaf(pr_[r], jv[u].y, acc[r][u*4+1]);
        acc[r][u*4+2] = fmaf(pr_[r], jv[u].z, acc[r][u*4+2]);
        acc[r][u*4+3] = fmaf(pr_[r], jv[u].w, acc[r][u*4+3]);
      }
    }
  }

  // per-lane rnj for its 16 j slots
  float4 rv[4];
#pragma unroll
  for (int u = 0; u < 4; ++u) rv[u] = *(const float4*)&rnjL[u * 256 + lane * 4];

  // ---- per-row exact top-32 + softmax, straight from registers ----
#pragma unroll
  for (int r = 0; r < 2; ++r) {
    const int rglob = w * 2 + r;
    const float sc = rnjL[i0 + rglob];         // rni == rnj of the row's point
    float v[16];
#pragma unroll
    for (int u = 0; u < 4; ++u) {
      v[u*4+0] = acc[r][u*4+0] * rv[u].x * sc;
      v[u*4+1] = acc[r][u*4+1] * rv[u].y * sc;
      v[u*4+2] = acc[r][u*4+2] * rv[u].z * sc;
      v[u*4+3] = acc[r][u*4+3] * rv[u].w * sc;
    }
    int q[16];
#pragma unroll
    for (int t = 0; t < 16; ++t) {
      float f = (v[t] + 1.0f) * 512.0f;        // monotone 10-bit quantization
      f = fminf(fmaxf(f, 0.0f), 1023.0f);
      q[t] = (int)f;
    }
    // largest lo with count(q >= lo) >= 32
    int lo = 0;
#pragma unroll
    for (int bit = 512; bit >= 1; bit >>= 1) {
      const int mid = lo + bit;
      int cnt = 0;
#pragma unroll
      for (int t = 0; t < 16; ++t) cnt += (int)__popcll(__ballot(q[t] >= mid));
      if (cnt >= KSEL) lo = mid;
    }
    // compact definite members (q > lo)
    int cbase = 0;
    unsigned cmask = 0u;
    const int thr = lo + 1;
#pragma unroll
    for (int t = 0; t < 16; ++t) {
      const bool hi = (q[t] >= thr);
      const unsigned long long m = __ballot(hi);
      if (hi) {
        const int pos = cbase + (int)__builtin_amdgcn_mbcnt_hi(
            (unsigned)(m >> 32), __builtin_amdgcn_mbcnt_lo((unsigned)m, 0u));
        const int j = (t >> 2) * 256 + lane * 4 + (t & 3);
        *(float2*)&cand[rglob][2 * pos] = make_float2(v[t], __int_as_float(j));
      }
      cbase += (int)__popcll(m);
      if (q[t] == lo) cmask |= (1u << t);
    }
    // boundary bin: exact (v desc, j asc) for remaining slots
    const int need = KSEL - cbase;
    for (int it = 0; it < need; ++it) {
      float bv = -2.0f; int bj = 0x7fffffff; int bt = 16;
#pragma unroll
      for (int t = 0; t < 16; ++t) {
        if (((cmask >> t) & 1u) && v[t] > bv) {
          bv = v[t]; bj = (t >> 2) * 256 + lane * 4 + (t & 3); bt = t;
        }
      }
      float rvv = bv; int rj = bj;
#pragma unroll
      for (int s = 1; s < 64; s <<= 1) {
        const float ov = __shfl_xor(rvv, s);
        const int   oj = __shfl_xor(rj, s);
        if (ov > rvv || (ov == rvv && oj < rj)) { rvv = ov; rj = oj; }
      }
      if (bv == rvv && bj == rj) {             // unique winner (j unique)
        *(float2*)&cand[rglob][2 * (cbase + it)] = make_float2(bv, __int_as_float(bj));
        cmask &= ~(1u << bt);
      }
    }
    // softmax over the selected 32 (order-invariant)
    {
      const float x = cand[rglob][2 * (lane & 31)];
      float mx = x;
#pragma unroll
      for (int s = 16; s >= 1; s >>= 1) mx = fmaxf(mx, __shfl_xor(mx, s));
      const float e = expf(x - mx);
      float sum = e;
#pragma unroll
      for (int s = 16; s >= 1; s >>= 1) sum += __shfl_xor(sum, s);
      if (lane < KSEL) cand[rglob][2 * lane] = e / sum;
    }
  }
  __syncthreads();

  // write (attn, id) pairs: one float2 per thread, coalesced
  {
    const int r = tid >> 5, k = tid & 31;
    *(float2*)&pairs[((size_t)batch * NPTS + i0 + r) * KSEL + k] =
        *(const float2*)&cand[r][2 * k];
  }
}

// ================= Kernel B: gather (broadcast-j, conflict-light) ===========
// 512 blocks x 256 threads; 32 rows/block; double-buffered global_load_lds.
__global__ __launch_bounds__(256, 2) void gnn_gather(const float* __restrict__ in,
                                                     const float2* __restrict__ pairs,
                                                     float* __restrict__ out) {
  __shared__ float fst[2][8 * 1028];   // 8 channel-rows per cc pass
  __shared__ float pr[32 * 68];        // [row][34 pairs]: a at 2k, j-bits at 2k+1

  const int p     = blockIdx.x;
  const int batch = ((p & 7) << 1) | ((p >> 3) & 1);
  const int chunk = p >> 4;            // 0..31
  const int i0    = chunk * 32;
  const int tid   = threadIdx.x;
  const int w     = tid >> 6;
  const int lane  = tid & 63;

  const float* __restrict__ fbase = in + (size_t)batch * CT * NPTS;

  // pairs -> LDS (1024 pairs = 512 float4)
  {
    const float4* pb4 = (const float4*)(pairs + ((size_t)batch * NPTS + i0) * KSEL);
#pragma unroll
    for (int h = 0; h < 2; ++h) {
      const int pidx = h * 256 + tid;          // float4 index: 2 pairs each
      const float4 q4 = pb4[pidx];
      const int r = pidx >> 4;                 // 16 float4 per row
      const int u = pidx & 15;
      *(float4*)&pr[r * 68 + u * 4] = q4;
    }
  }

  // stage helper: wave w stages channel-rows {2w, 2w+1} of pass cc into buf
#define STAGE(buf, ccv)                                                          \
  do {                                                                           \
    _Pragma("unroll")                                                            \
    for (int rr = 0; rr < 2; ++rr) {                                             \
      const int crow = w * 2 + rr;                                               \
      const float* src = fbase + (size_t)((ccv) * 8 + crow) * NPTS + lane * 4;   \
      float* dst = &fst[buf][crow * 1028];                                       \
      _Pragma("unroll")                                                          \
      for (int qq = 0; qq < 4; ++qq)                                             \
        __builtin_amdgcn_global_load_lds(                                        \
            (const __attribute__((address_space(1))) void*)(src + qq * 256),     \
            (__attribute__((address_space(3))) void*)(dst + qq * 256), 16, 0, 0);\
    }                                                                            \
  } while (0)

  STAGE(0, 0);
  asm volatile("s_waitcnt vmcnt(0)" ::: "memory");
  __syncthreads();

  const int c   = lane >> 3;           // channel slot 0..7
  const int rl  = lane & 7;
  const int row = w * 8 + rl;          // output row 0..31
  const float* prr = &pr[row * 68];

  for (int cc = 0; cc < 32; ++cc) {
    const int cur = cc & 1;
    if (cc < 31) STAGE(cur ^ 1, cc + 1);

    const float* fb = &fst[cur][c * 1028];
    float o = 0.f;
#pragma unroll
    for (int k = 0; k < KSEL; ++k) {
      const float2 pj = *(const float2*)&prr[2 * k];   // conflict-free broadcast
      o = fmaf(pj.x, fb[__float_as_int(pj.y)], o);     // 8 random j per instr
    }
    out[((size_t)batch * DFEAT + cc * 8 + c) * NPTS + i0 + row] = o;

    asm volatile("s_waitcnt vmcnt(0)" ::: "memory");
    __syncthreads();
  }
#undef STAGE
}

extern "C" void kernel_launch(void* const* d_in, const int* in_sizes, int n_in,
                              void* d_out, int out_size, void* d_ws, size_t ws_size,
                              hipStream_t stream) {
  const float* in = (const float*)d_in[0];
  float* out = (float*)d_out;
  float2* pairs = (float2*)d_ws;                         // 4 MB
  float*  rnjg  = (float*)((char*)d_ws + (16u << 20) / 4); // +4 MB: 64 KB table
  gnn_rnj<<<dim3(64), dim3(256), 0, stream>>>(in, rnjg);
  gnn_sim_topk<<<dim3(2048), dim3(256), 0, stream>>>(in, rnjg, pairs);
  gnn_gather<<<dim3(512), dim3(256), 0, stream>>>(in, pairs, out);
}

// Round 8
// 118.485 us; speedup vs baseline: 1.1459x; 1.1459x over previous
//
#include <hip/hip_runtime.h>
#include <math.h>

#define CT    320
#define NPTS  1024
#define DFEAT 256
#define DPOS  64
#define KSEL  32

// ============ Kernel C: per-point 1/max(||pos||,eps) -> rnjg (ws) ===========
// 64 blocks x 256 threads; block b: batch b>>2, j-segment (b&3)*256.
// Same fmaf chain order as the reference path -> bitwise-identical rnj.
__global__ void gnn_rnj(const float* __restrict__ in, float* __restrict__ rnjg) {
  const int b     = blockIdx.x;
  const int batch = b >> 2;
  const int j     = ((b & 3) << 8) + threadIdx.x;
  const float* __restrict__ pbase = in + (size_t)batch * CT * NPTS + (size_t)DFEAT * NPTS;
  float s = 0.f;
#pragma unroll 8
  for (int d = 0; d < DPOS; ++d) {
    const float x = pbase[(size_t)d * NPTS + j];
    s = fmaf(x, x, s);
  }
  rnjg[batch * NPTS + j] = 1.0f / fmaxf(sqrtf(s), 1e-12f);
}

// ================= Kernel A: sim + exact top-32 + softmax -> pairs(ws) ======
// Round-6 geometry (proven no-spill): 1024 blocks x 256 threads; 16 rows/blk;
// 4 blocks/CU. Wave owns 4 FULL rows (16 j/lane); exact top-32 from regs.
// Round-8 change: rnj comes from kernel C's table (4 KB) instead of a per-
// block 256 KB pos re-read (removes ~256 MB burst L2 traffic + latency chain).
#define AROWS 16
__global__ __launch_bounds__(256, 4) void gnn_sim_topk(const float* __restrict__ in,
                                                       const float* __restrict__ rnjg,
                                                       float2* __restrict__ pairs) {
  __shared__ float pi[DPOS * 20];      // [d][i], stride 20 (16B-aligned quads)
  __shared__ float rnjL[NPTS];
  __shared__ float cand[AROWS][68];    // 32 interleaved (v,j) pairs + pad

  const int p     = blockIdx.x;
  const int batch = ((p & 7) << 1) | ((p >> 3) & 1);   // 2 batches per XCD
  const int chunk = p >> 4;            // 0..63
  const int i0    = chunk * AROWS;
  const int tid   = threadIdx.x;
  const int w     = tid >> 6;
  const int lane  = tid & 63;

  const float* __restrict__ pbase = in + (size_t)batch * CT * NPTS + (size_t)DFEAT * NPTS;

  // stage raw pos of the 16 rows
  {
    const int i = tid & 15;
    const int d0 = tid >> 4;           // 0..15
#pragma unroll
    for (int pass = 0; pass < 4; ++pass) {
      const int d = pass * 16 + d0;
      pi[d * 20 + i] = pbase[(size_t)d * NPTS + i0 + i];
    }
  }
  // rnj table for this batch (4 KB, one float4 per thread)
  *(float4*)&rnjL[tid * 4] = *(const float4*)&rnjg[batch * NPTS + tid * 4];
  __syncthreads();

  // ---- sim: wave w owns rows w*4..w*4+3; lane owns j = u*256 + lane*4 + t ----
  float acc[4][16];
#pragma unroll
  for (int r = 0; r < 4; ++r)
#pragma unroll
    for (int s = 0; s < 16; ++s) acc[r][s] = 0.f;

  const float* jp = pbase + lane * 4;
#pragma unroll 2
  for (int d = 0; d < DPOS; ++d) {
    const float4 pv4 = *(const float4*)&pi[d * 20 + w * 4];   // broadcast
    const float pr_[4] = {pv4.x, pv4.y, pv4.z, pv4.w};
    float4 jv[4];
#pragma unroll
    for (int u = 0; u < 4; ++u)
      jv[u] = *(const float4*)(jp + (size_t)d * NPTS + u * 256);
#pragma unroll
    for (int r = 0; r < 4; ++r) {
#pragma unroll
      for (int u = 0; u < 4; ++u) {
        acc[r][u*4+0] = fmaf(pr_[r], jv[u].x, acc[r][u*4+0]);
        acc[r][u*4+1] = fmaf(pr_[r], jv[u].y, acc[r][u*4+1]);
        acc[r][u*4+2] = fmaf(pr_[r], jv[u].z, acc[r][u*4+2]);
        acc[r][u*4+3] = fmaf(pr_[r], jv[u].w, acc[r][u*4+3]);
      }
    }
  }

  // per-lane rnj for its 16 j slots
  float4 rv[4];
#pragma unroll
  for (int u = 0; u < 4; ++u) rv[u] = *(const float4*)&rnjL[u * 256 + lane * 4];

  // ---- per-row exact top-32 + softmax, straight from registers ----
#pragma unroll
  for (int r = 0; r < 4; ++r) {
    const int rglob = w * 4 + r;
    const float sc = rnjL[i0 + rglob];         // rni == rnj of the row's point
    float v[16];
#pragma unroll
    for (int u = 0; u < 4; ++u) {
      v[u*4+0] = acc[r][u*4+0] * rv[u].x * sc;
      v[u*4+1] = acc[r][u*4+1] * rv[u].y * sc;
      v[u*4+2] = acc[r][u*4+2] * rv[u].z * sc;
      v[u*4+3] = acc[r][u*4+3] * rv[u].w * sc;
    }
    int q[16];
#pragma unroll
    for (int t = 0; t < 16; ++t) {
      float f = (v[t] + 1.0f) * 512.0f;        // monotone 10-bit quantization
      f = fminf(fmaxf(f, 0.0f), 1023.0f);
      q[t] = (int)f;
    }
    // largest lo with count(q >= lo) >= 32
    int lo = 0;
#pragma unroll
    for (int bit = 512; bit >= 1; bit >>= 1) {
      const int mid = lo + bit;
      int cnt = 0;
#pragma unroll
      for (int t = 0; t < 16; ++t) cnt += (int)__popcll(__ballot(q[t] >= mid));
      if (cnt >= KSEL) lo = mid;
    }
    // compact definite members (q > lo)
    int cbase = 0;
    unsigned cmask = 0u;
    const int thr = lo + 1;
#pragma unroll
    for (int t = 0; t < 16; ++t) {
      const bool hi = (q[t] >= thr);
      const unsigned long long m = __ballot(hi);
      if (hi) {
        const int pos = cbase + (int)__builtin_amdgcn_mbcnt_hi(
            (unsigned)(m >> 32), __builtin_amdgcn_mbcnt_lo((unsigned)m, 0u));
        const int j = (t >> 2) * 256 + lane * 4 + (t & 3);
        *(float2*)&cand[rglob][2 * pos] = make_float2(v[t], __int_as_float(j));
      }
      cbase += (int)__popcll(m);
      if (q[t] == lo) cmask |= (1u << t);
    }
    // boundary bin: exact (v desc, j asc) for remaining slots
    const int need = KSEL - cbase;
    for (int it = 0; it < need; ++it) {
      float bv = -2.0f; int bj = 0x7fffffff; int bt = 16;
#pragma unroll
      for (int t = 0; t < 16; ++t) {
        if (((cmask >> t) & 1u) && v[t] > bv) {
          bv = v[t]; bj = (t >> 2) * 256 + lane * 4 + (t & 3); bt = t;
        }
      }
      float rvv = bv; int rj = bj;
#pragma unroll
      for (int s = 1; s < 64; s <<= 1) {
        const float ov = __shfl_xor(rvv, s);
        const int   oj = __shfl_xor(rj, s);
        if (ov > rvv || (ov == rvv && oj < rj)) { rvv = ov; rj = oj; }
      }
      if (bv == rvv && bj == rj) {             // unique winner (j unique)
        *(float2*)&cand[rglob][2 * (cbase + it)] = make_float2(bv, __int_as_float(bj));
        cmask &= ~(1u << bt);
      }
    }
    // softmax over the selected 32 (order-invariant)
    {
      const float x = cand[rglob][2 * (lane & 31)];
      float mx = x;
#pragma unroll
      for (int s = 16; s >= 1; s >>= 1) mx = fmaxf(mx, __shfl_xor(mx, s));
      const float e = expf(x - mx);
      float sum = e;
#pragma unroll
      for (int s = 16; s >= 1; s >>= 1) sum += __shfl_xor(sum, s);
      if (lane < KSEL) cand[rglob][2 * lane] = e / sum;
    }
  }
  __syncthreads();

  // write (attn, id) pairs, coalesced float4 (2 pairs per thread)
  {
    const int pidx = tid * 2;            // pair index
    const int r = pidx >> 5, k = pidx & 31;
    const float4 o4 = *(const float4*)&cand[r][2 * k];
    *(float4*)&pairs[((size_t)batch * NPTS + i0 + r) * KSEL + k] = o4;
  }
}

// ================= Kernel B: gather (broadcast-j, conflict-light) ===========
// 512 blocks x 256 threads; 32 rows/block; double-buffered global_load_lds.
__global__ __launch_bounds__(256, 2) void gnn_gather(const float* __restrict__ in,
                                                     const float2* __restrict__ pairs,
                                                     float* __restrict__ out) {
  __shared__ float fst[2][8 * 1028];   // 8 channel-rows per cc pass
  __shared__ float pr[32 * 68];        // [row][34 pairs]: a at 2k, j-bits at 2k+1

  const int p     = blockIdx.x;
  const int batch = ((p & 7) << 1) | ((p >> 3) & 1);
  const int chunk = p >> 4;            // 0..31
  const int i0    = chunk * 32;
  const int tid   = threadIdx.x;
  const int w     = tid >> 6;
  const int lane  = tid & 63;

  const float* __restrict__ fbase = in + (size_t)batch * CT * NPTS;

  // pairs -> LDS (1024 pairs = 512 float4)
  {
    const float4* pb4 = (const float4*)(pairs + ((size_t)batch * NPTS + i0) * KSEL);
#pragma unroll
    for (int h = 0; h < 2; ++h) {
      const int pidx = h * 256 + tid;          // float4 index: 2 pairs each
      const float4 q4 = pb4[pidx];
      const int r = pidx >> 4;                 // 16 float4 per row
      const int u = pidx & 15;
      *(float4*)&pr[r * 68 + u * 4] = q4;
    }
  }

  // stage helper: wave w stages channel-rows {2w, 2w+1} of pass cc into buf
#define STAGE(buf, ccv)                                                          \
  do {                                                                           \
    _Pragma("unroll")                                                            \
    for (int rr = 0; rr < 2; ++rr) {                                             \
      const int crow = w * 2 + rr;                                               \
      const float* src = fbase + (size_t)((ccv) * 8 + crow) * NPTS + lane * 4;   \
      float* dst = &fst[buf][crow * 1028];                                       \
      _Pragma("unroll")                                                          \
      for (int qq = 0; qq < 4; ++qq)                                             \
        __builtin_amdgcn_global_load_lds(                                        \
            (const __attribute__((address_space(1))) void*)(src + qq * 256),     \
            (__attribute__((address_space(3))) void*)(dst + qq * 256), 16, 0, 0);\
    }                                                                            \
  } while (0)

  STAGE(0, 0);
  asm volatile("s_waitcnt vmcnt(0)" ::: "memory");
  __syncthreads();

  const int c   = lane >> 3;           // channel slot 0..7
  const int rl  = lane & 7;
  const int row = w * 8 + rl;          // output row 0..31
  const float* prr = &pr[row * 68];

  for (int cc = 0; cc < 32; ++cc) {
    const int cur = cc & 1;
    if (cc < 31) STAGE(cur ^ 1, cc + 1);

    const float* fb = &fst[cur][c * 1028];
    float o = 0.f;
#pragma unroll
    for (int k = 0; k < KSEL; ++k) {
      const float2 pj = *(const float2*)&prr[2 * k];   // conflict-free broadcast
      o = fmaf(pj.x, fb[__float_as_int(pj.y)], o);     // 8 random j per instr
    }
    out[((size_t)batch * DFEAT + cc * 8 + c) * NPTS + i0 + row] = o;

    asm volatile("s_waitcnt vmcnt(0)" ::: "memory");
    __syncthreads();
  }
#undef STAGE
}

extern "C" void kernel_launch(void* const* d_in, const int* in_sizes, int n_in,
                              void* d_out, int out_size, void* d_ws, size_t ws_size,
                              hipStream_t stream) {
  const float* in = (const float*)d_in[0];
  float* out = (float*)d_out;
  float2* pairs = (float2*)d_ws;                           // 4 MB
  float*  rnjg  = (float*)((char*)d_ws + (16u << 20) / 4); // +4 MB: 64 KB table
  gnn_rnj<<<dim3(64), dim3(256), 0, stream>>>(in, rnjg);
  gnn_sim_topk<<<dim3(1024), dim3(256), 0, stream>>>(in, rnjg, pairs);
  gnn_gather<<<dim3(512), dim3(256), 0, stream>>>(in, pairs, out);
}

// Round 10
// 118.439 us; speedup vs baseline: 1.1463x; 1.0004x over previous
//
#include <hip/hip_runtime.h>
#include <math.h>

#define CT    320
#define NPTS  1024
#define DFEAT 256
#define DPOS  64
#define KSEL  32

// ============ Kernel C: per-point 1/max(||pos||,eps) -> rnjg (ws) ===========
// 64 blocks x 256 threads; block b: batch b>>2, j-segment (b&3)*256.
// Same fmaf chain order as the reference path -> bitwise-identical rnj.
__global__ void gnn_rnj(const float* __restrict__ in, float* __restrict__ rnjg) {
  const int b     = blockIdx.x;
  const int batch = b >> 2;
  const int j     = ((b & 3) << 8) + threadIdx.x;
  const float* __restrict__ pbase = in + (size_t)batch * CT * NPTS + (size_t)DFEAT * NPTS;
  float s = 0.f;
#pragma unroll 8
  for (int d = 0; d < DPOS; ++d) {
    const float x = pbase[(size_t)d * NPTS + j];
    s = fmaf(x, x, s);
  }
  rnjg[batch * NPTS + j] = 1.0f / fmaxf(sqrtf(s), 1e-12f);
}

// ================= Kernel A: sim + exact top-32 + softmax -> pairs(ws) ======
// 1024 blocks x 256 threads; 16 rows/blk; 4 blocks/CU. Wave owns 4 full rows.
// Round-9 change: j-data staged into LDS (2-d chunks, double-buffered
// global_load_lds) -- each block reads pos ONCE from L2 instead of 4x
// (1.07 GB -> 268 MB aggregate), and load latency hides behind compute.
#define AROWS 16
#define DCH   2                         // d-rows per staged chunk
__global__ __launch_bounds__(256, 4) void gnn_sim_topk(const float* __restrict__ in,
                                                       const float* __restrict__ rnjg,
                                                       float2* __restrict__ pairs) {
  __shared__ float pi[DPOS * 20];      // [d][i], stride 20 (16B-aligned quads)
  __shared__ float rnjL[NPTS];
  __shared__ float jt[2][DCH * 1024];  // staged j-chunks (8 KB each)
  __shared__ float cand[AROWS][68];    // 32 interleaved (v,j) pairs + pad

  const int p     = blockIdx.x;
  const int batch = ((p & 7) << 1) | ((p >> 3) & 1);   // 2 batches per XCD
  const int chunk = p >> 4;            // 0..63
  const int i0    = chunk * AROWS;
  const int tid   = threadIdx.x;
  const int w     = tid >> 6;
  const int lane  = tid & 63;

  const float* __restrict__ pbase = in + (size_t)batch * CT * NPTS + (size_t)DFEAT * NPTS;

  // stage raw pos of the 16 rows
  {
    const int i = tid & 15;
    const int d0 = tid >> 4;           // 0..15
#pragma unroll
    for (int pass = 0; pass < 4; ++pass) {
      const int d = pass * 16 + d0;
      pi[d * 20 + i] = pbase[(size_t)d * NPTS + i0 + i];
    }
  }
  // rnj table for this batch (4 KB, one float4 per thread)
  *(float4*)&rnjL[tid * 4] = *(const float4*)&rnjg[batch * NPTS + tid * 4];

  // j-chunk stage: wave w -> d-row (w>>1), half (w&1); 2 x 16B-wide async
#define JSTAGE(buf, c)                                                           \
  do {                                                                           \
    const int dd_   = (w >> 1);                                                  \
    const int half_ = (w & 1);                                                   \
    const float* src_ = pbase + (size_t)((c) * DCH + dd_) * NPTS + half_ * 512 + lane * 4; \
    float* dst_ = &jt[buf][dd_ * 1024 + half_ * 512];                            \
    __builtin_amdgcn_global_load_lds(                                            \
        (const __attribute__((address_space(1))) void*)(src_),                   \
        (__attribute__((address_space(3))) void*)(dst_), 16, 0, 0);              \
    __builtin_amdgcn_global_load_lds(                                            \
        (const __attribute__((address_space(1))) void*)(src_ + 256),             \
        (__attribute__((address_space(3))) void*)(dst_ + 256), 16, 0, 0);        \
  } while (0)

  JSTAGE(0, 0);
  asm volatile("s_waitcnt vmcnt(0)" ::: "memory");
  __syncthreads();                     // pi, rnjL, jt[0] ready

  // ---- sim: wave w owns rows w*4..w*4+3; lane owns j = u*256 + lane*4 + t ----
  float acc[4][16];
#pragma unroll
  for (int r = 0; r < 4; ++r)
#pragma unroll
    for (int s = 0; s < 16; ++s) acc[r][s] = 0.f;

  for (int c = 0; c < DPOS / DCH; ++c) {
    const int cur = c & 1;
    if (c < DPOS / DCH - 1) JSTAGE(cur ^ 1, c + 1);   // async into other buffer
#pragma unroll
    for (int dd = 0; dd < DCH; ++dd) {
      const int d = c * DCH + dd;
      const float4 pv4 = *(const float4*)&pi[d * 20 + w * 4];   // broadcast
      const float pr_[4] = {pv4.x, pv4.y, pv4.z, pv4.w};
      float4 jv[4];
#pragma unroll
      for (int u = 0; u < 4; ++u)
        jv[u] = *(const float4*)&jt[cur][dd * 1024 + u * 256 + lane * 4];
#pragma unroll
      for (int r = 0; r < 4; ++r) {
#pragma unroll
        for (int u = 0; u < 4; ++u) {
          acc[r][u*4+0] = fmaf(pr_[r], jv[u].x, acc[r][u*4+0]);
          acc[r][u*4+1] = fmaf(pr_[r], jv[u].y, acc[r][u*4+1]);
          acc[r][u*4+2] = fmaf(pr_[r], jv[u].z, acc[r][u*4+2]);
          acc[r][u*4+3] = fmaf(pr_[r], jv[u].w, acc[r][u*4+3]);
        }
      }
    }
    asm volatile("s_waitcnt vmcnt(0)" ::: "memory");   // staging landed
    __syncthreads();                                   // all waves done with cur
  }
#undef JSTAGE

  // per-lane rnj for its 16 j slots
  float4 rv[4];
#pragma unroll
  for (int u = 0; u < 4; ++u) rv[u] = *(const float4*)&rnjL[u * 256 + lane * 4];

  // ---- per-row exact top-32 + softmax, straight from registers ----
#pragma unroll
  for (int r = 0; r < 4; ++r) {
    const int rglob = w * 4 + r;
    const float sc = rnjL[i0 + rglob];         // rni == rnj of the row's point
    float v[16];
#pragma unroll
    for (int u = 0; u < 4; ++u) {
      v[u*4+0] = acc[r][u*4+0] * rv[u].x * sc;
      v[u*4+1] = acc[r][u*4+1] * rv[u].y * sc;
      v[u*4+2] = acc[r][u*4+2] * rv[u].z * sc;
      v[u*4+3] = acc[r][u*4+3] * rv[u].w * sc;
    }
    int q[16];
#pragma unroll
    for (int t = 0; t < 16; ++t) {
      float f = (v[t] + 1.0f) * 512.0f;        // monotone 10-bit quantization
      f = fminf(fmaxf(f, 0.0f), 1023.0f);
      q[t] = (int)f;
    }
    // largest lo with count(q >= lo) >= 32
    int lo = 0;
#pragma unroll
    for (int bit = 512; bit >= 1; bit >>= 1) {
      const int mid = lo + bit;
      int cnt = 0;
#pragma unroll
      for (int t = 0; t < 16; ++t) cnt += (int)__popcll(__ballot(q[t] >= mid));
      if (cnt >= KSEL) lo = mid;
    }
    // compact definite members (q > lo)
    int cbase = 0;
    unsigned cmask = 0u;
    const int thr = lo + 1;
#pragma unroll
    for (int t = 0; t < 16; ++t) {
      const bool hi = (q[t] >= thr);
      const unsigned long long m = __ballot(hi);
      if (hi) {
        const int pos = cbase + (int)__builtin_amdgcn_mbcnt_hi(
            (unsigned)(m >> 32), __builtin_amdgcn_mbcnt_lo((unsigned)m, 0u));
        const int j = (t >> 2) * 256 + lane * 4 + (t & 3);
        *(float2*)&cand[rglob][2 * pos] = make_float2(v[t], __int_as_float(j));
      }
      cbase += (int)__popcll(m);
      if (q[t] == lo) cmask |= (1u << t);
    }
    // boundary bin: exact (v desc, j asc) for remaining slots
    const int need = KSEL - cbase;
    for (int it = 0; it < need; ++it) {
      float bv = -2.0f; int bj = 0x7fffffff; int bt = 16;
#pragma unroll
      for (int t = 0; t < 16; ++t) {
        if (((cmask >> t) & 1u) && v[t] > bv) {
          bv = v[t]; bj = (t >> 2) * 256 + lane * 4 + (t & 3); bt = t;
        }
      }
      float rvv = bv; int rj = bj;
#pragma unroll
      for (int s = 1; s < 64; s <<= 1) {
        const float ov = __shfl_xor(rvv, s);
        const int   oj = __shfl_xor(rj, s);
        if (ov > rvv || (ov == rvv && oj < rj)) { rvv = ov; rj = oj; }
      }
      if (bv == rvv && bj == rj) {             // unique winner (j unique)
        *(float2*)&cand[rglob][2 * (cbase + it)] = make_float2(bv, __int_as_float(bj));
        cmask &= ~(1u << bt);
      }
    }
    // softmax over the selected 32 (order-invariant)
    {
      const float x = cand[rglob][2 * (lane & 31)];
      float mx = x;
#pragma unroll
      for (int s = 16; s >= 1; s >>= 1) mx = fmaxf(mx, __shfl_xor(mx, s));
      const float e = expf(x - mx);
      float sum = e;
#pragma unroll
      for (int s = 16; s >= 1; s >>= 1) sum += __shfl_xor(sum, s);
      if (lane < KSEL) cand[rglob][2 * lane] = e / sum;
    }
  }
  __syncthreads();

  // write (attn, id) pairs, coalesced float4 (2 pairs per thread)
  {
    const int pidx = tid * 2;            // pair index
    const int r = pidx >> 5, k = pidx & 31;
    const float4 o4 = *(const float4*)&cand[r][2 * k];
    *(float4*)&pairs[((size_t)batch * NPTS + i0 + r) * KSEL + k] = o4;
  }
}

// ================= Kernel B: gather (broadcast-j, conflict-light) ===========
// 512 blocks x 256 threads; 32 rows/block; double-buffered global_load_lds.
__global__ __launch_bounds__(256, 2) void gnn_gather(const float* __restrict__ in,
                                                     const float2* __restrict__ pairs,
                                                     float* __restrict__ out) {
  __shared__ float fst[2][8 * 1028];   // 8 channel-rows per cc pass
  __shared__ float pr[32 * 68];        // [row][34 pairs]: a at 2k, j-bits at 2k+1

  const int p     = blockIdx.x;
  const int batch = ((p & 7) << 1) | ((p >> 3) & 1);
  const int chunk = p >> 4;            // 0..31
  const int i0    = chunk * 32;
  const int tid   = threadIdx.x;
  const int w     = tid >> 6;
  const int lane  = tid & 63;

  const float* __restrict__ fbase = in + (size_t)batch * CT * NPTS;

  // pairs -> LDS (1024 pairs = 512 float4)
  {
    const float4* pb4 = (const float4*)(pairs + ((size_t)batch * NPTS + i0) * KSEL);
#pragma unroll
    for (int h = 0; h < 2; ++h) {
      const int pidx = h * 256 + tid;          // float4 index: 2 pairs each
      const float4 q4 = pb4[pidx];
      const int r = pidx >> 4;                 // 16 float4 per row
      const int u = pidx & 15;
      *(float4*)&pr[r * 68 + u * 4] = q4;
    }
  }

  // stage helper: wave w stages channel-rows {2w, 2w+1} of pass cc into buf
#define STAGE(buf, ccv)                                                          \
  do {                                                                           \
    _Pragma("unroll")                                                            \
    for (int rr = 0; rr < 2; ++rr) {                                             \
      const int crow = w * 2 + rr;                                               \
      const float* src = fbase + (size_t)((ccv) * 8 + crow) * NPTS + lane * 4;   \
      float* dst = &fst[buf][crow * 1028];                                       \
      _Pragma("unroll")                                                          \
      for (int qq = 0; qq < 4; ++qq)                                             \
        __builtin_amdgcn_global_load_lds(                                        \
            (const __attribute__((address_space(1))) void*)(src + qq * 256),     \
            (__attribute__((address_space(3))) void*)(dst + qq * 256), 16, 0, 0);\
    }                                                                            \
  } while (0)

  STAGE(0, 0);
  asm volatile("s_waitcnt vmcnt(0)" ::: "memory");
  __syncthreads();

  const int c   = lane >> 3;           // channel slot 0..7
  const int rl  = lane & 7;
  const int row = w * 8 + rl;          // output row 0..31
  const float* prr = &pr[row * 68];

  for (int cc = 0; cc < 32; ++cc) {
    const int cur = cc & 1;
    if (cc < 31) STAGE(cur ^ 1, cc + 1);

    const float* fb = &fst[cur][c * 1028];
    float o = 0.f;
#pragma unroll
    for (int k = 0; k < KSEL; ++k) {
      const float2 pj = *(const float2*)&prr[2 * k];   // conflict-free broadcast
      o = fmaf(pj.x, fb[__float_as_int(pj.y)], o);     // 8 random j per instr
    }
    out[((size_t)batch * DFEAT + cc * 8 + c) * NPTS + i0 + row] = o;

    asm volatile("s_waitcnt vmcnt(0)" ::: "memory");
    __syncthreads();
  }
#undef STAGE
}

extern "C" void kernel_launch(void* const* d_in, const int* in_sizes, int n_in,
                              void* d_out, int out_size, void* d_ws, size_t ws_size,
                              hipStream_t stream) {
  const float* in = (const float*)d_in[0];
  float* out = (float*)d_out;
  float2* pairs = (float2*)d_ws;                           // 4 MB
  float*  rnjg  = (float*)((char*)d_ws + (16u << 20) / 4); // +4 MB: 64 KB table
  gnn_rnj<<<dim3(64), dim3(256), 0, stream>>>(in, rnjg);
  gnn_sim_topk<<<dim3(1024), dim3(256), 0, stream>>>(in, rnjg, pairs);
  gnn_gather<<<dim3(512), dim3(256), 0, stream>>>(in, pairs, out);
}

// Round 11
// 112.298 us; speedup vs baseline: 1.2090x; 1.0547x over previous
//
#include <hip/hip_runtime.h>
#include <math.h>

#define CT    320
#define NPTS  1024
#define DFEAT 256
#define DPOS  64
#define KSEL  32

// ============ Kernel C: per-point 1/max(||pos||,eps) -> rnjg (ws) ===========
__global__ void gnn_rnj(const float* __restrict__ in, float* __restrict__ rnjg) {
  const int b     = blockIdx.x;
  const int batch = b >> 2;
  const int j     = ((b & 3) << 8) + threadIdx.x;
  const float* __restrict__ pbase = in + (size_t)batch * CT * NPTS + (size_t)DFEAT * NPTS;
  float s = 0.f;
#pragma unroll 8
  for (int d = 0; d < DPOS; ++d) {
    const float x = pbase[(size_t)d * NPTS + j];
    s = fmaf(x, x, s);
  }
  rnjg[batch * NPTS + j] = 1.0f / fmaxf(sqrtf(s), 1e-12f);
}

// ================= Kernel A: sim + exact top-32 + softmax -> pairs(ws) ======
// 1024 blocks x 256 threads; 16 rows/blk; 4 blocks/CU. Wave owns 4 full rows.
// Round-11: (1) float-threshold 15-bit binary search (no quantization pass;
// boundary bin ~1 element -> serial shfl need-loop ~1 iter instead of ~4);
// (2) triple-buffered j-staging with counted vmcnt(2) -- never drain to 0
// in the main loop (T4).
#define AROWS 16
#define DCH   2                         // d-rows per staged chunk
#define QSTEP 6.103515625e-05f          // 2^-14, thr(m) = m*QSTEP - 1 (exact)
__global__ __launch_bounds__(256, 4) void gnn_sim_topk(const float* __restrict__ in,
                                                       const float* __restrict__ rnjg,
                                                       float2* __restrict__ pairs) {
  __shared__ float pi[DPOS * 20];      // [d][i], stride 20 (16B-aligned quads)
  __shared__ float rnjL[NPTS];
  __shared__ float jt[3][DCH * 1024];  // staged j-chunks (8 KB each), 3-deep
  __shared__ float cand[AROWS][68];    // 32 interleaved (v,j) pairs + pad

  const int p     = blockIdx.x;
  const int batch = ((p & 7) << 1) | ((p >> 3) & 1);   // 2 batches per XCD
  const int chunk = p >> 4;            // 0..63
  const int i0    = chunk * AROWS;
  const int tid   = threadIdx.x;
  const int w     = tid >> 6;
  const int lane  = tid & 63;

  const float* __restrict__ pbase = in + (size_t)batch * CT * NPTS + (size_t)DFEAT * NPTS;

  // stage raw pos of the 16 rows
  {
    const int i = tid & 15;
    const int d0 = tid >> 4;           // 0..15
#pragma unroll
    for (int pass = 0; pass < 4; ++pass) {
      const int d = pass * 16 + d0;
      pi[d * 20 + i] = pbase[(size_t)d * NPTS + i0 + i];
    }
  }
  // rnj table for this batch (4 KB, one float4 per thread)
  *(float4*)&rnjL[tid * 4] = *(const float4*)&rnjg[batch * NPTS + tid * 4];

  // j-chunk stage: wave w -> d-row (w>>1), half (w&1); 2 x 16B-wide async
#define JSTAGE(buf, c)                                                           \
  do {                                                                           \
    const int dd_   = (w >> 1);                                                  \
    const int half_ = (w & 1);                                                   \
    const float* src_ = pbase + (size_t)((c) * DCH + dd_) * NPTS + half_ * 512 + lane * 4; \
    float* dst_ = &jt[buf][dd_ * 1024 + half_ * 512];                            \
    __builtin_amdgcn_global_load_lds(                                            \
        (const __attribute__((address_space(1))) void*)(src_),                   \
        (__attribute__((address_space(3))) void*)(dst_), 16, 0, 0);              \
    __builtin_amdgcn_global_load_lds(                                            \
        (const __attribute__((address_space(1))) void*)(src_ + 256),             \
        (__attribute__((address_space(3))) void*)(dst_ + 256), 16, 0, 0);        \
  } while (0)

  JSTAGE(0, 0);
  JSTAGE(1, 1);
  asm volatile("s_waitcnt vmcnt(2)" ::: "memory");   // chunk 0 landed; 1 in flight
  __syncthreads();                     // pi, rnjL, jt[0] ready

  // ---- sim: wave w owns rows w*4..w*4+3; lane owns j = u*256 + lane*4 + t ----
  float acc[4][16];
#pragma unroll
  for (int r = 0; r < 4; ++r)
#pragma unroll
    for (int s = 0; s < 16; ++s) acc[r][s] = 0.f;

  int cur = 0;
  for (int c = 0; c < DPOS / DCH; ++c) {
#pragma unroll
    for (int dd = 0; dd < DCH; ++dd) {
      const int d = c * DCH + dd;
      const float4 pv4 = *(const float4*)&pi[d * 20 + w * 4];   // broadcast
      const float pr_[4] = {pv4.x, pv4.y, pv4.z, pv4.w};
      float4 jv[4];
#pragma unroll
      for (int u = 0; u < 4; ++u)
        jv[u] = *(const float4*)&jt[cur][dd * 1024 + u * 256 + lane * 4];
#pragma unroll
      for (int r = 0; r < 4; ++r) {
#pragma unroll
        for (int u = 0; u < 4; ++u) {
          acc[r][u*4+0] = fmaf(pr_[r], jv[u].x, acc[r][u*4+0]);
          acc[r][u*4+1] = fmaf(pr_[r], jv[u].y, acc[r][u*4+1]);
          acc[r][u*4+2] = fmaf(pr_[r], jv[u].z, acc[r][u*4+2]);
          acc[r][u*4+3] = fmaf(pr_[r], jv[u].w, acc[r][u*4+3]);
        }
      }
    }
    // stage 2 ahead; counted wait: next chunk landed, newest still in flight
    if (c < DPOS / DCH - 2) {
      const int nbuf = (cur + 2 >= 3) ? cur - 1 : cur + 2;
      JSTAGE(nbuf, c + 2);
      asm volatile("s_waitcnt vmcnt(2)" ::: "memory");
    } else {
      asm volatile("s_waitcnt vmcnt(0)" ::: "memory");
    }
    __syncthreads();                   // readers of overwritten buf are >=1 BAR back
    cur = (cur + 1 >= 3) ? 0 : cur + 1;
  }
#undef JSTAGE

  // per-lane rnj for its 16 j slots
  float4 rv[4];
#pragma unroll
  for (int u = 0; u < 4; ++u) rv[u] = *(const float4*)&rnjL[u * 256 + lane * 4];

  // ---- per-row exact top-32 + softmax, straight from registers ----
#pragma unroll
  for (int r = 0; r < 4; ++r) {
    const int rglob = w * 4 + r;
    const float sc = rnjL[i0 + rglob];         // rni == rnj of the row's point
    float v[16];
#pragma unroll
    for (int u = 0; u < 4; ++u) {
      v[u*4+0] = acc[r][u*4+0] * rv[u].x * sc;
      v[u*4+1] = acc[r][u*4+1] * rv[u].y * sc;
      v[u*4+2] = acc[r][u*4+2] * rv[u].z * sc;
      v[u*4+3] = acc[r][u*4+3] * rv[u].w * sc;
    }
    // 15-bit float-threshold search: largest lo with count(v >= thr(lo)) >= 32
    // thr(m) = m*2^-14 - 1 is EXACT in fp32 for m in [0, 32768] -> selection
    // semantics identical to exact top-k with (v desc, j asc) tie-break.
    int lo = 0;
#pragma unroll
    for (int bit = 16384; bit >= 1; bit >>= 1) {
      const float thrf = (float)(lo + bit) * QSTEP - 1.0f;
      int cnt = 0;
#pragma unroll
      for (int t = 0; t < 16; ++t) cnt += (int)__popcll(__ballot(v[t] >= thrf));
      if (cnt >= KSEL) lo += bit;
    }
    const float thr_h = (float)(lo + 1) * QSTEP - 1.0f;   // definite threshold
    const float thr_l = (float)lo * QSTEP - 1.0f;         // boundary low edge
    // compact definite members (v >= thr_h); boundary bin -> cmask
    int cbase = 0;
    unsigned cmask = 0u;
#pragma unroll
    for (int t = 0; t < 16; ++t) {
      const bool hi = (v[t] >= thr_h);
      const unsigned long long m = __ballot(hi);
      if (hi) {
        const int pos = cbase + (int)__builtin_amdgcn_mbcnt_hi(
            (unsigned)(m >> 32), __builtin_amdgcn_mbcnt_lo((unsigned)m, 0u));
        const int j = (t >> 2) * 256 + lane * 4 + (t & 3);
        *(float2*)&cand[rglob][2 * pos] = make_float2(v[t], __int_as_float(j));
      }
      cbase += (int)__popcll(m);
      if ((v[t] >= thr_l) && !hi) cmask |= (1u << t);
    }
    // boundary: exact (v desc, j asc); at 2^-14 bins this runs ~1 iteration
    const int need = KSEL - cbase;
    for (int it = 0; it < need; ++it) {
      float bv = -2.0f; int bj = 0x7fffffff; int bt = 16;
#pragma unroll
      for (int t = 0; t < 16; ++t) {
        if (((cmask >> t) & 1u) && v[t] > bv) {
          bv = v[t]; bj = (t >> 2) * 256 + lane * 4 + (t & 3); bt = t;
        }
      }
      float rvv = bv; int rj = bj;
#pragma unroll
      for (int s = 1; s < 64; s <<= 1) {
        const float ov = __shfl_xor(rvv, s);
        const int   oj = __shfl_xor(rj, s);
        if (ov > rvv || (ov == rvv && oj < rj)) { rvv = ov; rj = oj; }
      }
      if (bv == rvv && bj == rj) {             // unique winner (j unique)
        *(float2*)&cand[rglob][2 * (cbase + it)] = make_float2(bv, __int_as_float(bj));
        cmask &= ~(1u << bt);
      }
    }
    // softmax over the selected 32 (order-invariant)
    {
      const float x = cand[rglob][2 * (lane & 31)];
      float mx = x;
#pragma unroll
      for (int s = 16; s >= 1; s >>= 1) mx = fmaxf(mx, __shfl_xor(mx, s));
      const float e = expf(x - mx);
      float sum = e;
#pragma unroll
      for (int s = 16; s >= 1; s >>= 1) sum += __shfl_xor(sum, s);
      if (lane < KSEL) cand[rglob][2 * lane] = e / sum;
    }
  }
  __syncthreads();

  // write (attn, id) pairs, coalesced float4 (2 pairs per thread)
  {
    const int pidx = tid * 2;            // pair index
    const int r = pidx >> 5, k = pidx & 31;
    const float4 o4 = *(const float4*)&cand[r][2 * k];
    *(float4*)&pairs[((size_t)batch * NPTS + i0 + r) * KSEL + k] = o4;
  }
}

// ================= Kernel B: gather (broadcast-j, conflict-light) ===========
// 512 blocks x 256 threads; 32 rows/block; double-buffered global_load_lds.
__global__ __launch_bounds__(256, 2) void gnn_gather(const float* __restrict__ in,
                                                     const float2* __restrict__ pairs,
                                                     float* __restrict__ out) {
  __shared__ float fst[2][8 * 1028];   // 8 channel-rows per cc pass
  __shared__ float pr[32 * 68];        // [row][34 pairs]: a at 2k, j-bits at 2k+1

  const int p     = blockIdx.x;
  const int batch = ((p & 7) << 1) | ((p >> 3) & 1);
  const int chunk = p >> 4;            // 0..31
  const int i0    = chunk * 32;
  const int tid   = threadIdx.x;
  const int w     = tid >> 6;
  const int lane  = tid & 63;

  const float* __restrict__ fbase = in + (size_t)batch * CT * NPTS;

  // pairs -> LDS (1024 pairs = 512 float4)
  {
    const float4* pb4 = (const float4*)(pairs + ((size_t)batch * NPTS + i0) * KSEL);
#pragma unroll
    for (int h = 0; h < 2; ++h) {
      const int pidx = h * 256 + tid;          // float4 index: 2 pairs each
      const float4 q4 = pb4[pidx];
      const int r = pidx >> 4;                 // 16 float4 per row
      const int u = pidx & 15;
      *(float4*)&pr[r * 68 + u * 4] = q4;
    }
  }

  // stage helper: wave w stages channel-rows {2w, 2w+1} of pass cc into buf
#define STAGE(buf, ccv)                                                          \
  do {                                                                           \
    _Pragma("unroll")                                                            \
    for (int rr = 0; rr < 2; ++rr) {                                             \
      const int crow = w * 2 + rr;                                               \
      const float* src = fbase + (size_t)((ccv) * 8 + crow) * NPTS + lane * 4;   \
      float* dst = &fst[buf][crow * 1028];                                       \
      _Pragma("unroll")                                                          \
      for (int qq = 0; qq < 4; ++qq)                                             \
        __builtin_amdgcn_global_load_lds(                                        \
            (const __attribute__((address_space(1))) void*)(src + qq * 256),     \
            (__attribute__((address_space(3))) void*)(dst + qq * 256), 16, 0, 0);\
    }                                                                            \
  } while (0)

  STAGE(0, 0);
  asm volatile("s_waitcnt vmcnt(0)" ::: "memory");
  __syncthreads();

  const int c   = lane >> 3;           // channel slot 0..7
  const int rl  = lane & 7;
  const int row = w * 8 + rl;          // output row 0..31
  const float* prr = &pr[row * 68];

  for (int cc = 0; cc < 32; ++cc) {
    const int cur = cc & 1;
    if (cc < 31) STAGE(cur ^ 1, cc + 1);

    const float* fb = &fst[cur][c * 1028];
    float o = 0.f;
#pragma unroll
    for (int k = 0; k < KSEL; ++k) {
      const float2 pj = *(const float2*)&prr[2 * k];   // conflict-free broadcast
      o = fmaf(pj.x, fb[__float_as_int(pj.y)], o);     // 8 random j per instr
    }
    out[((size_t)batch * DFEAT + cc * 8 + c) * NPTS + i0 + row] = o;

    asm volatile("s_waitcnt vmcnt(0)" ::: "memory");
    __syncthreads();
  }
#undef STAGE
}

extern "C" void kernel_launch(void* const* d_in, const int* in_sizes, int n_in,
                              void* d_out, int out_size, void* d_ws, size_t ws_size,
                              hipStream_t stream) {
  const float* in = (const float*)d_in[0];
  float* out = (float*)d_out;
  float2* pairs = (float2*)d_ws;                           // 4 MB
  float*  rnjg  = (float*)((char*)d_ws + (16u << 20) / 4); // +4 MB: 64 KB table
  gnn_rnj<<<dim3(64), dim3(256), 0, stream>>>(in, rnjg);
  gnn_sim_topk<<<dim3(1024), dim3(256), 0, stream>>>(in, rnjg, pairs);
  gnn_gather<<<dim3(512), dim3(256), 0, stream>>>(in, pairs, out);
}